// Round 3
// baseline (2124.725 us; speedup 1.0000x reference)
//
#include <hip/hip_runtime.h>
#include <hip/hip_fp16.h>

// LightGCN 3-layer propagation, fp16 ego intermediates.
// Round 9b: compile fix only (nontemporal store needs a native vector
// type, not HIP_vector_type<float,2> — use ext_vector_type(2)).
// Round 9: gather was latency-bound (deg~13 -> ~2-iter loops, 24 shuffles,
// divergent epilogue; 43% HBM / 39% VALU / nothing saturated). New gather:
// one block per src-bucket, fp32 accumulators for the whole bucket
// (293x64, padded to 65) live in LDS, edges consumed UNSORTED within the
// bucket via ds_add_f32 atomics. This deletes csr_finalize + pairs +
// rowPtr (the within-bucket counting sort existed only to make register
// accumulation possible) and turns the gather into long uniform streams:
// 32 half-wave edge streams/block x 2 edges in flight, no shuffles.

#define NUM_USERS 100000
#define NUM_ITEMS 50000
#define EMB_DIM   64
#define N_EDGES   2000000
#define N_NODES   (NUM_USERS + NUM_ITEMS)          // 150000
#define NODE_FLOATS (N_NODES * EMB_DIM)            // 9,600,000
#define NODE_F4     (NODE_FLOATS / 4)              // 2,400,000

#define NBUCKET  512
#define NPB      293        // nodes per bucket; 512*293 = 150016 >= 150000
#define NPART    8          // reservation partitions (XCD heuristic)
#define NCNT     (NBUCKET * NPART)                  // 4096
#define BT       512        // threads in bucket passes
#define VPT      8          // edges per thread in bucket passes
#define TILE     (BT * VPT)                         // 4096
#define NTILE    ((N_EDGES + TILE - 1) / TILE)      // 489

#define GT       1024       // gather threads (32 half-wave streams)
#define ACC_LD   65         // padded LDS row stride (odd -> banks spread)

typedef unsigned int uint;
typedef unsigned short ushort;
typedef unsigned long long u64;
typedef __attribute__((ext_vector_type(2))) float fv2;

__device__ __forceinline__ float2 h2f2(uint u) {
    __half2 h = *reinterpret_cast<const __half2*>(&u);
    return __half22float2(h);
}
__device__ __forceinline__ uint f2h2(float a, float b) {
    __half2 h = __floats2half2_rn(a, b);
    return *reinterpret_cast<uint*>(&h);
}

// ---------- init: egoA(fp16) = concat(user,item) ----------
__global__ void lgcn_init(const float4* __restrict__ user,
                          const float4* __restrict__ item,
                          uint2* __restrict__ egoA) {
    const int n_user4 = NUM_USERS * EMB_DIM / 4;
    for (int i = blockIdx.x * blockDim.x + threadIdx.x; i < NODE_F4;
         i += gridDim.x * blockDim.x) {
        float4 v = (i < n_user4) ? user[i] : item[i - n_user4];
        egoA[i] = make_uint2(f2h2(v.x, v.y), f2h2(v.z, v.w));
    }
}

__global__ void zero_ints(int* __restrict__ p, int n) {
    int i = blockIdx.x * blockDim.x + threadIdx.x;
    if (i < n) p[i] = 0;
}

// ---------- pass A: histogram into (bucket, partition) counters ----------
__global__ __launch_bounds__(BT) void bucket_hist(const int* __restrict__ src,
                                                  int* __restrict__ bucketCount) {
    __shared__ int cnt[NBUCKET];
    int t = threadIdx.x;
    int part = blockIdx.x & (NPART - 1);
    cnt[t] = 0;
    __syncthreads();
    int base = blockIdx.x * TILE + t;
    #pragma unroll
    for (int k = 0; k < VPT; ++k) {
        int e = base + k * BT;
        if (e < N_EDGES) atomicAdd(&cnt[src[e] / NPB], 1);
    }
    __syncthreads();
    int c = cnt[t];
    if (c) atomicAdd(&bucketCount[t * NPART + part], c);
}

// ---------- scan over 4096 (bucket,part) counters (1 block, 1024 thr) ----------
__global__ __launch_bounds__(1024) void bucket_scan(const int* __restrict__ bucketCount,
                                                    int* __restrict__ bucketOffset,
                                                    int* __restrict__ gCur) {
    __shared__ int s[1024];
    int t = threadIdx.x;
    int4 c = *(const int4*)(bucketCount + t * 4);
    int sum = c.x + c.y + c.z + c.w;
    s[t] = sum;
    __syncthreads();
    for (int off = 1; off < 1024; off <<= 1) {
        int x = (t >= off) ? s[t - off] : 0;
        __syncthreads();
        s[t] += x;
        __syncthreads();
    }
    int base = s[t] - sum;   // exclusive
    int i0 = t * 4;
    bucketOffset[i0]     = base;
    bucketOffset[i0 + 1] = base + c.x;
    bucketOffset[i0 + 2] = base + c.x + c.y;
    bucketOffset[i0 + 3] = base + c.x + c.y + c.z;
    gCur[i0]     = base;
    gCur[i0 + 1] = base + c.x;
    gCur[i0 + 2] = base + c.x + c.y;
    gCur[i0 + 3] = base + c.x + c.y + c.z;
    if (t == 0) bucketOffset[NCNT] = N_EDGES;
}

// ---------- pass B: scatter packed edges into (bucket,part) runs ----------
// packed u64: [norm:32][src_local:9][dst:18]
__global__ __launch_bounds__(BT) void bucket_scatter(const int* __restrict__ src,
                                                     const int* __restrict__ dst,
                                                     const float* __restrict__ norm,
                                                     int* __restrict__ gCur,
                                                     u64* __restrict__ bpair) {
    __shared__ int cnt[NBUCKET];
    __shared__ int bbase[NBUCKET];
    int t = threadIdx.x;
    int part = blockIdx.x & (NPART - 1);
    cnt[t] = 0;
    __syncthreads();
    int base = blockIdx.x * TILE + t;
    #pragma unroll
    for (int k = 0; k < VPT; ++k) {
        int e = base + k * BT;
        if (e < N_EDGES) atomicAdd(&cnt[src[e] / NPB], 1);
    }
    __syncthreads();
    int c = cnt[t];
    bbase[t] = c ? atomicAdd(&gCur[t * NPART + part], c) : 0;
    __syncthreads();
    cnt[t] = 0;
    __syncthreads();
    #pragma unroll
    for (int k = 0; k < VPT; ++k) {
        int e = base + k * BT;
        if (e < N_EDGES) {
            int s = src[e];
            int b = s / NPB;
            int sl = s - b * NPB;                    // 0..292
            int r = atomicAdd(&cnt[b], 1);
            uint lo = (uint)dst[e] | ((uint)sl << 18);
            u64 packed = (u64)lo | ((u64)(uint)__float_as_uint(norm[e]) << 32);
            bpair[bbase[b] + r] = packed;
        }
    }
}

// ---------- gather: 1 bucket/block, fp32 LDS accumulators, unsorted edges ----
// finalMode==0: nego = fp16(s)
// finalMode==1: acc  = (e0 + e1 + ego + s) * 0.25
__global__ __launch_bounds__(GT) void lgcn_gather_lds(
        const ushort* __restrict__ ego,
        ushort* __restrict__ nego,
        float* __restrict__ acc,
        const ushort* __restrict__ e0,
        const ushort* __restrict__ e1,
        const int* __restrict__ bucketOffset,
        const u64* __restrict__ bpair,
        int finalMode) {
    __shared__ float accs[NPB * ACC_LD];              // 76,180 B (2 blocks/CU)
    int b = blockIdx.x;
    int t = threadIdx.x;
    int beg = bucketOffset[b * NPART];
    int end = bucketOffset[(b + 1) * NPART];

    for (int i = t; i < NPB * ACC_LD; i += GT) accs[i] = 0.f;
    __syncthreads();

    int hw = t >> 5;            // 32 half-wave edge streams
    int l  = t & 31;            // lane within half-wave: dims 2l, 2l+1
    for (int i = beg + hw; i < end; i += 64) {
        int i2 = i + 32;
        u64 pA = __builtin_nontemporal_load(&bpair[i]);
        u64 pB = (i2 < end) ? __builtin_nontemporal_load(&bpair[i2])
                            : (u64)0;                 // w=0 -> harmless add
        uint loA = (uint)pA, loB = (uint)pB;
        float wA = __uint_as_float((uint)(pA >> 32));
        float wB = __uint_as_float((uint)(pB >> 32));
        uint rA = *(const uint*)(ego + ((size_t)(loA & 0x3FFFF) << 6) + (l << 1));
        uint rB = *(const uint*)(ego + ((size_t)(loB & 0x3FFFF) << 6) + (l << 1));
        int slA = (loA >> 18) & 0x1FF;
        int slB = (loB >> 18) & 0x1FF;
        float2 qA = h2f2(rA);
        float2 qB = h2f2(rB);
        atomicAdd(&accs[slA * ACC_LD + 2 * l],     wA * qA.x);
        atomicAdd(&accs[slA * ACC_LD + 2 * l + 1], wA * qA.y);
        atomicAdd(&accs[slB * ACC_LD + 2 * l],     wB * qB.x);
        atomicAdd(&accs[slB * ACC_LD + 2 * l + 1], wB * qB.y);
    }
    __syncthreads();

    int nodeBase = b * NPB;
    int nrows = N_NODES - nodeBase;
    if (nrows > NPB) nrows = NPB;

    if (!finalMode) {
        uint* np = (uint*)nego;
        for (int idx = t; idx < nrows * 32; idx += GT) {
            int row = idx >> 5, dp = idx & 31;
            float x = accs[row * ACC_LD + 2 * dp];
            float y = accs[row * ACC_LD + 2 * dp + 1];
            np[((size_t)(nodeBase + row) << 5) + dp] = f2h2(x, y);
        }
    } else {
        const uint* p0 = (const uint*)e0;
        const uint* p1 = (const uint*)e1;
        const uint* p2 = (const uint*)ego;
        fv2* ap = (fv2*)acc;
        for (int idx = t; idx < nrows * 32; idx += GT) {
            int row = idx >> 5, dp = idx & 31;
            size_t o = ((size_t)(nodeBase + row) << 5) + dp;
            float sx = accs[row * ACC_LD + 2 * dp];
            float sy = accs[row * ACC_LD + 2 * dp + 1];
            float2 a = h2f2(__builtin_nontemporal_load(&p0[o]));
            float2 bb = h2f2(__builtin_nontemporal_load(&p1[o]));
            float2 c = h2f2(__builtin_nontemporal_load(&p2[o]));
            fv2 ov;
            ov.x = (a.x + bb.x + c.x + sx) * 0.25f;
            ov.y = (a.y + bb.y + c.y + sy) * 0.25f;
            __builtin_nontemporal_store(ov, &ap[o]);
        }
    }
}

extern "C" void kernel_launch(void* const* d_in, const int* in_sizes, int n_in,
                              void* d_out, int out_size, void* d_ws, size_t ws_size,
                              hipStream_t stream) {
    const float* user_emb  = (const float*)d_in[0];
    const float* item_emb  = (const float*)d_in[1];
    const float* edge_norm = (const float*)d_in[2];
    const int*   edge_src  = (const int*)d_in[3];
    const int*   edge_dst  = (const int*)d_in[4];
    float* acc = (float*)d_out;

    char* w = (char*)d_ws;
    ushort* egoA  = (ushort*)w;                      w += (size_t)NODE_FLOATS * 2;   // 19.2 MB
    ushort* egoB  = (ushort*)w;                      w += (size_t)NODE_FLOATS * 2;   // 19.2 MB
    ushort* egoC  = (ushort*)w;                      w += (size_t)NODE_FLOATS * 2;   // 19.2 MB
    u64*   bpair  = (u64*)w;                         w += (size_t)N_EDGES * 8;       // 16 MB
    int*   bucketCount  = (int*)w;                   w += (size_t)NCNT * 4;
    int*   bucketOffset = (int*)w;                   w += (size_t)(NCNT + 4) * 4;
    int*   gCur   = (int*)w;

    const int T = 256;
    const int EW_BLOCKS = 2048;

    lgcn_init<<<EW_BLOCKS, T, 0, stream>>>(
        (const float4*)user_emb, (const float4*)item_emb, (uint2*)egoA);

    zero_ints<<<NCNT / T, T, 0, stream>>>(bucketCount, NCNT);
    bucket_hist<<<NTILE, BT, 0, stream>>>(edge_src, bucketCount);
    bucket_scan<<<1, 1024, 0, stream>>>(bucketCount, bucketOffset, gCur);
    bucket_scatter<<<NTILE, BT, 0, stream>>>(edge_src, edge_dst, edge_norm,
                                             gCur, bpair);

    // Layer 1: ego0(A) -> ego1(B)
    lgcn_gather_lds<<<NBUCKET, GT, 0, stream>>>(egoA, egoB, acc,
                                                (const ushort*)0, (const ushort*)0,
                                                bucketOffset, bpair, 0);
    // Layer 2: ego1(B) -> ego2(C)
    lgcn_gather_lds<<<NBUCKET, GT, 0, stream>>>(egoB, egoC, acc,
                                                (const ushort*)0, (const ushort*)0,
                                                bucketOffset, bpair, 0);
    // Layer 3: ego2(C) -> s; acc = (A + B + C + s) / 4
    lgcn_gather_lds<<<NBUCKET, GT, 0, stream>>>(egoC, (ushort*)0, acc,
                                                egoA, egoB,
                                                bucketOffset, bpair, 1);
}